// Round 16
// baseline (460.033 us; speedup 1.0000x reference)
//
#include <hip/hip_runtime.h>

#define NN 100000
#define NE 1250000
#define FIN 32
#define HD 64
#define NR 8
#define NG 256
#define BN_EPS 1e-5f
#define PCH 100          // nodes per pooling block (divides NN)
#define M_KEYS (NN * NR) // 800000 (dst,rel) count slots
#define NBN 98           // node-scan blocks: 98*1024 >= 100000
#define RREP 32          // BN-stat atomic replicas
#define HW 576           // h width: 8 rel * 64 + root 64

#if defined(__has_builtin)
#if __has_builtin(__builtin_amdgcn_fdot2_f32_bf16)
#define USE_DOT2 1
#endif
#endif
#ifndef USE_DOT2
#define USE_DOT2 0
#endif

typedef unsigned short ushort_t;
typedef __attribute__((ext_vector_type(8))) short short8;
typedef __attribute__((ext_vector_type(4))) float f32x4;
typedef __attribute__((ext_vector_type(4))) unsigned int u32x4;
#if USE_DOT2
typedef __bf16 bf16x2 __attribute__((ext_vector_type(2)));
#endif

static __device__ __forceinline__ ushort_t f2bf(float f) {
  unsigned u = __float_as_uint(f);
  u += 0x7fffu + ((u >> 16) & 1u);  // RNE
  return (ushort_t)(u >> 16);
}
static __device__ __forceinline__ float bf2f(ushort_t b) {
  return __uint_as_float((unsigned)b << 16);
}

__global__ void k_zero(float* __restrict__ p, int n) {
  int i = blockIdx.x * 256 + threadIdx.x;
  if (i < n) p[i] = 0.0f;
}

// pass 1: per-(dst,rel) counts only (no rank — edge order within a node is free)
__global__ void k_cnt(const int* __restrict__ dst, const int* __restrict__ ty,
                      unsigned* __restrict__ cnt8) {
  int e = blockIdx.x * 256 + threadIdx.x;
  if (e < NE) atomicAdd(&cnt8[dst[e] * NR + ty[e]], 1u);
}

// node-degree scan (100K): deg[n] = sum_r cnt8[n*8+r]
__global__ void k_scanA(const unsigned* __restrict__ cnt8, unsigned* __restrict__ bsum) {
  __shared__ unsigned red[256];
  int t = threadIdx.x;
  int base = blockIdx.x * 1024 + t * 4;
  unsigned s = 0;
  #pragma unroll
  for (int i = 0; i < 4; i++) {
    int nd = base + i;
    if (nd < NN) {
      const u32x4* p = (const u32x4*)(cnt8 + (size_t)nd * NR);
      u32x4 v0 = p[0], v1 = p[1];
      s += v0[0] + v0[1] + v0[2] + v0[3] + v1[0] + v1[1] + v1[2] + v1[3];
    }
  }
  red[t] = s;
  __syncthreads();
  for (int off = 128; off > 0; off >>= 1) {
    if (t < off) red[t] += red[t + off];
    __syncthreads();
  }
  if (t == 0) bsum[blockIdx.x] = red[0];
}

__global__ __launch_bounds__(1024) void k_scanB(const unsigned* __restrict__ bsum,
                                                unsigned* __restrict__ boff,
                                                int* __restrict__ rowstart) {
  __shared__ unsigned sb[1024];
  int t = threadIdx.x;
  unsigned mine = (t < NBN) ? bsum[t] : 0u;
  sb[t] = mine;
  __syncthreads();
  for (int off = 1; off < 1024; off <<= 1) {
    unsigned v = (t >= off) ? sb[t - off] : 0u;
    __syncthreads();
    sb[t] += v;
    __syncthreads();
  }
  if (t < NBN) boff[t] = sb[t] - mine;
  if (t == 1023) rowstart[NN] = (int)sb[1023];
}

// writes rowstart[node] and a working copy pos[node] for the place pass
__global__ void k_scanC(const unsigned* __restrict__ cnt8, const unsigned* __restrict__ boff,
                        int* __restrict__ rowstart, int* __restrict__ pos) {
  __shared__ unsigned sb[256];
  int t = threadIdx.x;
  int base = blockIdx.x * 1024 + t * 4;
  unsigned d[4];
  unsigned tot = 0;
  #pragma unroll
  for (int i = 0; i < 4; i++) {
    unsigned s = 0;
    int nd = base + i;
    if (nd < NN) {
      const u32x4* p = (const u32x4*)(cnt8 + (size_t)nd * NR);
      u32x4 v0 = p[0], v1 = p[1];
      s = v0[0] + v0[1] + v0[2] + v0[3] + v1[0] + v1[1] + v1[2] + v1[3];
    }
    d[i] = s;
    tot += s;
  }
  sb[t] = tot;
  __syncthreads();
  for (int off = 1; off < 256; off <<= 1) {
    unsigned v = (t >= off) ? sb[t - off] : 0u;
    __syncthreads();
    sb[t] += v;
    __syncthreads();
  }
  unsigned run = boff[blockIdx.x] + (sb[t] - tot);
  #pragma unroll
  for (int i = 0; i < 4; i++) {
    int nd = base + i;
    if (nd < NN) { rowstart[nd] = (int)run; pos[nd] = (int)run; }
    run += d[i];
  }
}

// pass 2: slot via atomicAdd on pos[dst] (400KB, L2-hot); record packs
// pre-multiplied h element offset + rel
__global__ void k_place(const int* __restrict__ src, const int* __restrict__ dst,
                        const int* __restrict__ ty, int* __restrict__ pos,
                        unsigned* __restrict__ eb) {
  int e = blockIdx.x * 256 + threadIdx.x;
  if (e < NE) {
    int t = ty[e];
    int d = dst[e];
    unsigned off = (unsigned)(src[e] * HW + t * 64);
    int p = atomicAdd(&pos[d], 1);
    eb[p] = (off << 3) | (unsigned)t;
  }
}

// wt[c][k] bf16, c<576 output cols of [W_0..W_7 | root], k<F
template <int F>
__global__ void k_wconv(const float* __restrict__ convw, const float* __restrict__ root,
                        ushort_t* __restrict__ wt) {
  int i = blockIdx.x * 256 + threadIdx.x;  // over 576*F
  if (i >= 576 * F) return;
  int c = i / F, k = i % F;
  float v = (c < 512) ? convw[((size_t)(c >> 6) * F + k) * 64 + (c & 63)]
                      : root[(size_t)k * 64 + (c & 63)];
  wt[(size_t)c * F + k] = f2bf(v);
}

// Persistent fused BN+ReLU+hi/lo-split + MFMA xform (round-12/13 proven).
template <int F, bool APPLY_BN>
__global__ __launch_bounds__(256) void k_xmm(
    const float* __restrict__ xin, const float* __restrict__ scsh,
    const ushort_t* __restrict__ wt, ushort_t* __restrict__ h) {
  constexpr int KK = 2 * F;
  constexpr int XPAD = KK + 8;
  constexpr int LDR = 592;
  __shared__ ushort_t xs[16 * XPAD];
  __shared__ ushort_t ot[16 * LDR];
  int lane = threadIdx.x & 63;
  int w = threadIdx.x >> 6;
  int m = lane & 15;
  int q = lane >> 4;
  int ct0 = w * 9;

  short8 bfrag[9 * (F / 32)];
  #pragma unroll
  for (int ks = 0; ks < F / 32; ks++)
    #pragma unroll
    for (int t = 0; t < 9; t++)
      bfrag[ks * 9 + t] =
          *(const short8*)(wt + (size_t)((ct0 + t) * 16 + m) * F + ks * 32 + q * 8);

  for (int tile = blockIdx.x; tile < NN / 16; tile += gridDim.x) {
    int nbase = tile * 16;
    for (int i = threadIdx.x; i < 16 * F; i += 256) {
      int r = i / F, k = i - r * F;
      float v = xin[(size_t)(nbase + r) * F + k];
      if (APPLY_BN) v = fmaxf(fmaf(v, scsh[k], scsh[64 + k]), 0.0f);
      ushort_t hi = f2bf(v);
      xs[r * XPAD + k] = hi;
      xs[r * XPAD + F + k] = f2bf(v - bf2f(hi));
    }
    __syncthreads();

    short8 afrag[2 * (F / 32)];
    #pragma unroll
    for (int ks = 0; ks < F / 32; ks++) {
      afrag[2 * ks + 0] = *(const short8*)&xs[m * XPAD + ks * 32 + q * 8];
      afrag[2 * ks + 1] = *(const short8*)&xs[m * XPAD + F + ks * 32 + q * 8];
    }

    f32x4 acc[9];
    #pragma unroll
    for (int t = 0; t < 9; t++) acc[t] = (f32x4){0.f, 0.f, 0.f, 0.f};
    #pragma unroll
    for (int ks = 0; ks < F / 32; ks++) {
      #pragma unroll
      for (int t = 0; t < 9; t++) {
        acc[t] = __builtin_amdgcn_mfma_f32_16x16x32_bf16(afrag[2 * ks + 0],
                                                         bfrag[ks * 9 + t], acc[t], 0, 0, 0);
        acc[t] = __builtin_amdgcn_mfma_f32_16x16x32_bf16(afrag[2 * ks + 1],
                                                         bfrag[ks * 9 + t], acc[t], 0, 0, 0);
      }
    }
    #pragma unroll
    for (int t = 0; t < 9; t++) {
      int col = (ct0 + t) * 16 + m;
      #pragma unroll
      for (int j = 0; j < 4; j++) {
        int row = q * 4 + j;
        ot[row * LDR + col] = f2bf(acc[t][j]);
      }
    }
    __syncthreads();
    u32x4* dst = (u32x4*)(h + (size_t)nbase * HW);
    for (int idx = threadIdx.x; idx < 16 * 72; idx += 256) {
      int row = idx / 72, i = idx - row * 72;
      dst[row * 72 + i] = *(const u32x4*)&ot[row * LDR + i * 8];
    }
  }
}

// Two-nodes-per-wave aggregation: each 32-lane half owns one node; 4 edge
// streams x 8 lanes x uint4 (8 bf16 channels) per half; invcnt from cnt8
// (contiguous 32B per node); per-pair perm+dot2; 2-level shfl_xor combine.
// Fixed costs (iclu/shfl/epilogue/BN-reduce) amortize over 2 nodes.
__global__ __launch_bounds__(256) void k_agg4(
    const ushort_t* __restrict__ h, const int* __restrict__ rowstart,
    const unsigned* __restrict__ cnt8, const unsigned* __restrict__ eb,
    const float* __restrict__ bias, float* __restrict__ outp,
    float* __restrict__ statsrep) {
  __shared__ float red[1024];      // [0..511] sums, [512..1023] squares (8 nodes x 64)
  __shared__ ushort_t iclu[8][8];
  int lane = threadIdx.x & 63, w = threadIdx.x >> 6;
  int hw = lane >> 5;              // half 0/1
  int nd = w * 2 + hw;             // node slot 0..7
  int n = blockIdx.x * 8 + nd;
  int l32 = lane & 31;
  if (l32 < 8) {
    unsigned c = cnt8[(size_t)n * NR + l32];
    iclu[nd][l32] = f2bf(1.0f / (float)(c > 1u ? c : 1u));
  }
  int lo = rowstart[n];
  int cnt = rowstart[n + 1] - lo;
  __syncthreads();
  int g = (lane >> 3) & 3;         // stream in half
  int c8 = (lane & 7) * 8;         // channel base
  int cntmax = max(cnt, __shfl_xor(cnt, 32));
  float a[8];
  #pragma unroll
  for (int j = 0; j < 8; j++) a[j] = 0.f;
  for (int base = 0; base < cntmax; base += 16) {
    unsigned rec[4]; u32x4 hv[4]; unsigned icb[4];
    #pragma unroll
    for (int s = 0; s < 4; s++) {
      int el = base + s * 4 + g;
      int ee = (el < cnt) ? el : (cnt > 0 ? cnt - 1 : 0);
      rec[s] = eb[lo + ee];
      icb[s] = (el < cnt) ? (unsigned)iclu[nd][rec[s] & 7] : 0u;
    }
    #pragma unroll
    for (int s = 0; s < 4; s++)
      hv[s] = *(const u32x4*)(h + (size_t)(rec[s] >> 3) + c8);
#if USE_DOT2
    #pragma unroll
    for (int s = 0; s < 4; s += 2) {
      unsigned b01 = __builtin_amdgcn_perm(icb[s + 1], icb[s], 0x05040100u);
      bf16x2 bb = __builtin_bit_cast(bf16x2, b01);
      #pragma unroll
      for (int k = 0; k < 4; k++) {
        unsigned plo = __builtin_amdgcn_perm(hv[s + 1][k], hv[s][k], 0x05040100u);
        unsigned phi = __builtin_amdgcn_perm(hv[s + 1][k], hv[s][k], 0x07060302u);
        a[2 * k + 0] = __builtin_amdgcn_fdot2_f32_bf16(
            __builtin_bit_cast(bf16x2, plo), bb, a[2 * k + 0], false);
        a[2 * k + 1] = __builtin_amdgcn_fdot2_f32_bf16(
            __builtin_bit_cast(bf16x2, phi), bb, a[2 * k + 1], false);
      }
    }
#else
    #pragma unroll
    for (int s = 0; s < 4; s++) {
      float ic = bf2f((ushort_t)icb[s]);
      #pragma unroll
      for (int k = 0; k < 4; k++) {
        a[2 * k + 0] = fmaf(__uint_as_float(hv[s][k] << 16), ic, a[2 * k + 0]);
        a[2 * k + 1] = fmaf(__uint_as_float(hv[s][k] & 0xffff0000u), ic, a[2 * k + 1]);
      }
    }
#endif
  }
  #pragma unroll
  for (int j = 0; j < 8; j++) {
    a[j] += __shfl_xor(a[j], 8);
    a[j] += __shfl_xor(a[j], 16);
  }
  if (g == 0) {  // lanes l32<8 hold the final 8-channel sums for node nd
    u32x4 sv = *(const u32x4*)(h + (size_t)n * HW + 512 + c8);
    float4 b4lo = *(const float4*)(bias + c8);
    float4 b4hi = *(const float4*)(bias + c8 + 4);
    float d[8];
    d[0] = a[0] + __uint_as_float(sv[0] << 16) + b4lo.x;
    d[1] = a[1] + __uint_as_float(sv[0] & 0xffff0000u) + b4lo.y;
    d[2] = a[2] + __uint_as_float(sv[1] << 16) + b4lo.z;
    d[3] = a[3] + __uint_as_float(sv[1] & 0xffff0000u) + b4lo.w;
    d[4] = a[4] + __uint_as_float(sv[2] << 16) + b4hi.x;
    d[5] = a[5] + __uint_as_float(sv[2] & 0xffff0000u) + b4hi.y;
    d[6] = a[6] + __uint_as_float(sv[3] << 16) + b4hi.z;
    d[7] = a[7] + __uint_as_float(sv[3] & 0xffff0000u) + b4hi.w;
    float4 lo4 = make_float4(d[0], d[1], d[2], d[3]);
    float4 hi4 = make_float4(d[4], d[5], d[6], d[7]);
    *(float4*)(outp + (size_t)n * HD + c8) = lo4;
    *(float4*)(outp + (size_t)n * HD + c8 + 4) = hi4;
    *(float4*)(&red[nd * 64 + c8]) = lo4;
    *(float4*)(&red[nd * 64 + c8 + 4]) = hi4;
    *(float4*)(&red[512 + nd * 64 + c8]) =
        make_float4(d[0] * d[0], d[1] * d[1], d[2] * d[2], d[3] * d[3]);
    *(float4*)(&red[512 + nd * 64 + c8 + 4]) =
        make_float4(d[4] * d[4], d[5] * d[5], d[6] * d[6], d[7] * d[7]);
  }
  __syncthreads();
  if (w == 0) {
    float ts = 0.f, tss = 0.f;
    #pragma unroll
    for (int k = 0; k < 8; k++) {
      ts += red[k * 64 + lane];
      tss += red[512 + k * 64 + lane];
    }
    int rp = blockIdx.x & (RREP - 1);
    atomicAdd(&statsrep[rp * 128 + lane], ts);
    atomicAdd(&statsrep[rp * 128 + 64 + lane], tss);
  }
}

// reduce stat replicas -> BN (scale, shift)
__global__ void k_finstats(const float* __restrict__ rep, const float* __restrict__ g,
                           const float* __restrict__ b, float* __restrict__ scsh) {
  int lane = threadIdx.x;  // 64
  float s = 0.f, ss = 0.f;
  for (int rp = 0; rp < RREP; rp++) {
    s += rep[rp * 128 + lane];
    ss += rep[rp * 128 + 64 + lane];
  }
  float mu = s * (1.0f / NN);
  float var = ss * (1.0f / NN) - mu * mu;
  float sc = g[lane] * rsqrtf(var + BN_EPS);
  scsh[lane] = sc;
  scsh[64 + lane] = b[lane] - mu * sc;
}

// sorted-batch segmented pooling over RAW layer outputs with inline BN+ReLU.
__global__ void k_poolseg(const float* __restrict__ t1, const float* __restrict__ t2,
                          const float* __restrict__ t3, const float* __restrict__ scsh,
                          const int* __restrict__ batch, float* __restrict__ psum,
                          unsigned* __restrict__ pmax, float* __restrict__ cntg) {
  __shared__ int bsh[PCH];
  int base = blockIdx.x * PCH;
  int c = threadIdx.x;  // 0..191
  for (int i = c; i < PCH; i += 192) bsh[i] = batch[base + i];
  __syncthreads();
  int L = c >> 6, cc = c & 63;
  const float* xs = (L == 0) ? t1 : (L == 1) ? t2 : t3;
  float sc = scsh[L * 128 + cc], sh = scsh[L * 128 + 64 + cc];
  int cur = bsh[0];
  float sum = 0.0f, mx = 0.0f;
  int runlen = 0;
  #pragma unroll 4
  for (int i = 0; i < PCH; i++) {
    int g = bsh[i];
    float v = fmaxf(fmaf(xs[(size_t)(base + i) * 64 + cc], sc, sh), 0.0f);
    if (g != cur) {  // wave-uniform, rare
      atomicAdd(&psum[cur * 192 + c], sum);
      atomicMax(&pmax[cur * 192 + c], __float_as_uint(mx));
      if (c == 0) atomicAdd(&cntg[cur], (float)runlen);
      cur = g; sum = 0.0f; mx = 0.0f; runlen = 0;
    }
    sum += v;
    mx = fmaxf(mx, v);
    runlen++;
  }
  atomicAdd(&psum[cur * 192 + c], sum);
  atomicMax(&pmax[cur * 192 + c], __float_as_uint(mx));
  if (c == 0) atomicAdd(&cntg[cur], (float)runlen);
}

__global__ void k_fc1(const float* __restrict__ psum, const unsigned* __restrict__ pmax,
                      const float* __restrict__ cntg, const float* __restrict__ w,
                      const float* __restrict__ bias, float* __restrict__ h1) {
  __shared__ float a[384];
  int g = blockIdx.x;
  float ic = 1.0f / fmaxf(cntg[g], 1.0f);
  for (int c = threadIdx.x; c < 384; c += 128) {
    a[c] = (c < 192) ? psum[g * 192 + c] * ic : __uint_as_float(pmax[g * 192 + (c - 192)]);
  }
  __syncthreads();
  int j = threadIdx.x;
  float acc = bias[j];
  for (int k = 0; k < 384; k++) acc = fmaf(a[k], w[k * 128 + j], acc);
  h1[g * 128 + j] = acc;
}

__global__ void k_fcbn_stats(const float* __restrict__ h1, const float* __restrict__ g,
                             const float* __restrict__ b, float* __restrict__ scsh) {
  __shared__ float sr[512], ssr[512];
  int j = threadIdx.x & 127, q = threadIdx.x >> 7;
  float s = 0.f, ss = 0.f;
  for (int i = q * 64; i < q * 64 + 64; i++) {
    float v = h1[i * 128 + j];
    s += v;
    ss = fmaf(v, v, ss);
  }
  sr[threadIdx.x] = s;
  ssr[threadIdx.x] = ss;
  __syncthreads();
  if (q == 0) {
    s = sr[j] + sr[128 + j] + sr[256 + j] + sr[384 + j];
    ss = ssr[j] + ssr[128 + j] + ssr[256 + j] + ssr[384 + j];
    float mu = s * (1.0f / NG);
    float var = ss * (1.0f / NG) - mu * mu;
    float sc = g[j] * rsqrtf(var + BN_EPS);
    scsh[j] = sc;
    scsh[128 + j] = b[j] - mu * sc;
  }
}

__global__ void k_leaky(float* __restrict__ h1, const float* __restrict__ scsh) {
  int j = threadIdx.x;
  int g = blockIdx.x;
  float v = fmaf(h1[g * 128 + j], scsh[j], scsh[128 + j]);
  h1[g * 128 + j] = v > 0.0f ? v : 0.2f * v;
}

__global__ void k_head(const float* __restrict__ h1, const float* __restrict__ fc2w,
                       const float* __restrict__ fc2b, const float* __restrict__ d1w,
                       const float* __restrict__ d1b, const float* __restrict__ d2w,
                       const float* __restrict__ d2b, float* __restrict__ out) {
  __shared__ float emb[16];
  int g = blockIdx.x;
  int t = threadIdx.x;  // 0..63
  if (t < 16) {
    float acc = fc2b[t];
    for (int k = 0; k < 128; k++) acc = fmaf(h1[g * 128 + k], fc2w[k * 16 + t], acc);
    emb[t] = acc;
    out[NG + g * 16 + t] = acc;
  }
  __syncthreads();
  float acc = d1b[t];
  for (int k = 0; k < 16; k++) acc = fmaf(emb[k], d1w[k * 64 + t], acc);
  acc = acc > 0.0f ? acc : 0.2f * acc;
  float p = acc * d2w[t];
  for (int off = 32; off > 0; off >>= 1) p += __shfl_down(p, off);
  if (t == 0) out[g] = p + d2b[0];
}

extern "C" void kernel_launch(void* const* d_in, const int* in_sizes, int n_in,
                              void* d_out, int out_size, void* d_ws, size_t ws_size,
                              hipStream_t stream) {
  const float* x    = (const float*)d_in[0];
  const int*   ei   = (const int*)d_in[1];
  const int*   ety  = (const int*)d_in[2];
  const int*   batch= (const int*)d_in[3];
  const float* c1w  = (const float*)d_in[4];
  const float* c1r  = (const float*)d_in[5];
  const float* c1b  = (const float*)d_in[6];
  const float* bn1g = (const float*)d_in[7];
  const float* bn1b = (const float*)d_in[8];
  const float* c2w  = (const float*)d_in[9];
  const float* c2r  = (const float*)d_in[10];
  const float* c2b  = (const float*)d_in[11];
  const float* bn2g = (const float*)d_in[12];
  const float* bn2b = (const float*)d_in[13];
  const float* c3w  = (const float*)d_in[14];
  const float* c3r  = (const float*)d_in[15];
  const float* c3b  = (const float*)d_in[16];
  const float* bn3g = (const float*)d_in[17];
  const float* bn3b = (const float*)d_in[18];
  const float* fc1w = (const float*)d_in[19];
  const float* fc1b = (const float*)d_in[20];
  const float* fbg  = (const float*)d_in[21];
  const float* fbb  = (const float*)d_in[22];
  const float* fc2w = (const float*)d_in[23];
  const float* fc2b = (const float*)d_in[24];
  const float* d1w  = (const float*)d_in[25];
  const float* d1b  = (const float*)d_in[26];
  const float* d2w  = (const float*)d_in[27];
  const float* d2b  = (const float*)d_in[28];
  const int* esrc = ei;
  const int* edst = ei + NE;
  float* out = (float*)d_out;

  float* W = (float*)d_ws;
  size_t o = 0;
  auto alloc = [&](size_t n) { float* p = W + o; o += (n + 63) & ~(size_t)63; return p; };
  unsigned* cnt8     = (unsigned*)alloc(M_KEYS);
  float*    psum     = alloc(NG * 192);
  unsigned* pmax     = (unsigned*)alloc(NG * 192);
  float*    cntg     = alloc(NG);
  float*    statsrep = alloc(3 * RREP * 128);
  size_t zone = o;  // buffers [0, zone) zeroed every call
  int*      rowstart = (int*)alloc(NN + 1);
  int*      pos  = (int*)alloc(NN + 1);
  unsigned* eb   = (unsigned*)alloc(NE);
  unsigned* bsum = (unsigned*)alloc(1024);
  unsigned* boff = (unsigned*)alloc(1024);
  float*    scsh = alloc(3 * 128);
  float*    fcsc = alloc(256);
  float*    h1   = alloc(NG * 128);
  float*    tmp1 = alloc((size_t)NN * HD);
  float*    tmp2 = alloc((size_t)NN * HD);
  float*    tmp3 = alloc((size_t)NN * HD);
  ushort_t* hbig = (ushort_t*)alloc((size_t)NN * HW / 2);  // bf16 h
  ushort_t* wt1  = (ushort_t*)alloc(576 * FIN / 2);
  ushort_t* wt2  = (ushort_t*)alloc(576 * HD / 2);
  ushort_t* wt3  = (ushort_t*)alloc(576 * HD / 2);
  (void)ws_size; (void)in_sizes; (void)n_in; (void)out_size;

  // ---- preprocess: dst-level CSR + per-(dst,rel) counts ----
  k_zero<<<(int)((zone + 255) / 256), 256, 0, stream>>>(W, (int)zone);
  k_cnt<<<(NE + 255) / 256, 256, 0, stream>>>(edst, ety, cnt8);
  k_scanA<<<NBN, 256, 0, stream>>>(cnt8, bsum);
  k_scanB<<<1, 1024, 0, stream>>>(bsum, boff, rowstart);
  k_scanC<<<NBN, 256, 0, stream>>>(cnt8, boff, rowstart, pos);
  k_place<<<(NE + 255) / 256, 256, 0, stream>>>(esrc, edst, ety, pos, eb);
  k_wconv<FIN><<<(576 * FIN + 255) / 256, 256, 0, stream>>>(c1w, c1r, wt1);
  k_wconv<HD><<<(576 * HD + 255) / 256, 256, 0, stream>>>(c2w, c2r, wt2);
  k_wconv<HD><<<(576 * HD + 255) / 256, 256, 0, stream>>>(c3w, c3r, wt3);

  // ---- layers: persistent fused MFMA xform -> 2-node/wave aggregate ----
  k_xmm<FIN, false><<<2048, 256, 0, stream>>>(x, nullptr, wt1, hbig);
  k_agg4<<<NN / 8, 256, 0, stream>>>(hbig, rowstart, cnt8, eb, c1b, tmp1, statsrep);
  k_finstats<<<1, 64, 0, stream>>>(statsrep, bn1g, bn1b, scsh);

  k_xmm<HD, true><<<2048, 256, 0, stream>>>(tmp1, scsh, wt2, hbig);
  k_agg4<<<NN / 8, 256, 0, stream>>>(hbig, rowstart, cnt8, eb, c2b, tmp2, statsrep + RREP * 128);
  k_finstats<<<1, 64, 0, stream>>>(statsrep + RREP * 128, bn2g, bn2b, scsh + 128);

  k_xmm<HD, true><<<2048, 256, 0, stream>>>(tmp2, scsh + 128, wt3, hbig);
  k_agg4<<<NN / 8, 256, 0, stream>>>(hbig, rowstart, cnt8, eb, c3b, tmp3, statsrep + 2 * RREP * 128);
  k_finstats<<<1, 64, 0, stream>>>(statsrep + 2 * RREP * 128, bn3g, bn3b, scsh + 256);

  // ---- pooling + head ----
  k_poolseg<<<NN / PCH, 192, 0, stream>>>(tmp1, tmp2, tmp3, scsh, batch, psum, pmax, cntg);
  k_fc1<<<NG, 128, 0, stream>>>(psum, pmax, cntg, fc1w, fc1b, h1);
  k_fcbn_stats<<<1, 512, 0, stream>>>(h1, fbg, fbb, fcsc);
  k_leaky<<<NG, 128, 0, stream>>>(h1, fcsc);
  k_head<<<NG, 64, 0, stream>>>(h1, fc2w, fc2b, d1w, d1b, d2w, d2b, out);
}

// Round 17
// 409.397 us; speedup vs baseline: 1.1237x; 1.1237x over previous
//
#include <hip/hip_runtime.h>

#define NN 100000
#define NE 1250000
#define FIN 32
#define HD 64
#define NR 8
#define NG 256
#define BN_EPS 1e-5f
#define PCH 100          // nodes per pooling block (divides NN)
#define M_KEYS (NN * NR) // 800000 (dst,rel) segments
#define NB 782           // scan blocks: 782*1024 >= 800000
#define RREP 32          // BN-stat atomic replicas
#define HW 576           // h width: 8 rel * 64 + root 64

#if defined(__has_builtin)
#if __has_builtin(__builtin_amdgcn_fdot2_f32_bf16)
#define USE_DOT2 1
#endif
#endif
#ifndef USE_DOT2
#define USE_DOT2 0
#endif

typedef unsigned short ushort_t;
typedef __attribute__((ext_vector_type(8))) short short8;
typedef __attribute__((ext_vector_type(4))) float f32x4;
typedef __attribute__((ext_vector_type(4))) unsigned int u32x4;
#if USE_DOT2
typedef __bf16 bf16x2 __attribute__((ext_vector_type(2)));
#endif

static __device__ __forceinline__ ushort_t f2bf(float f) {
  unsigned u = __float_as_uint(f);
  u += 0x7fffu + ((u >> 16) & 1u);  // RNE
  return (ushort_t)(u >> 16);
}
static __device__ __forceinline__ float bf2f(ushort_t b) {
  return __uint_as_float((unsigned)b << 16);
}

__global__ void k_zero(float* __restrict__ p, int n) {
  int i = blockIdx.x * 256 + threadIdx.x;
  if (i < n) p[i] = 0.0f;
}

// pass 1: per-(dst,rel) counts + per-edge rank (800K slots -> low contention)
__global__ void k_cnt(const int* __restrict__ dst, const int* __restrict__ ty,
                      unsigned* __restrict__ cnt, int* __restrict__ rank) {
  int e = blockIdx.x * 256 + threadIdx.x;
  if (e < NE) {
    int key = dst[e] * NR + ty[e];
    rank[e] = (int)atomicAdd(&cnt[key], 1u);
  }
}

// hierarchical exclusive scan of cnt[M_KEYS] -> rowstart[M_KEYS+1]
__global__ void k_scanA(const unsigned* __restrict__ cnt, unsigned* __restrict__ bsum) {
  __shared__ unsigned red[256];
  int t = threadIdx.x;
  int base = blockIdx.x * 1024 + t * 4;
  unsigned s = 0;
  #pragma unroll
  for (int i = 0; i < 4; i++) {
    int idx = base + i;
    if (idx < M_KEYS) s += cnt[idx];
  }
  red[t] = s;
  __syncthreads();
  for (int off = 128; off > 0; off >>= 1) {
    if (t < off) red[t] += red[t + off];
    __syncthreads();
  }
  if (t == 0) bsum[blockIdx.x] = red[0];
}

__global__ __launch_bounds__(1024) void k_scanB(const unsigned* __restrict__ bsum,
                                                unsigned* __restrict__ boff,
                                                int* __restrict__ rowstart) {
  __shared__ unsigned sb[1024];
  int t = threadIdx.x;
  unsigned mine = (t < NB) ? bsum[t] : 0u;
  sb[t] = mine;
  __syncthreads();
  for (int off = 1; off < 1024; off <<= 1) {
    unsigned v = (t >= off) ? sb[t - off] : 0u;
    __syncthreads();
    sb[t] += v;
    __syncthreads();
  }
  if (t < NB) boff[t] = sb[t] - mine;
  if (t == 1023) rowstart[M_KEYS] = (int)sb[1023];
}

__global__ void k_scanC(const unsigned* __restrict__ cnt, const unsigned* __restrict__ boff,
                        int* __restrict__ rowstart) {
  __shared__ unsigned sb[256];
  int t = threadIdx.x;
  int base = blockIdx.x * 1024 + t * 4;
  unsigned c0 = (base + 0 < M_KEYS) ? cnt[base + 0] : 0u;
  unsigned c1 = (base + 1 < M_KEYS) ? cnt[base + 1] : 0u;
  unsigned c2 = (base + 2 < M_KEYS) ? cnt[base + 2] : 0u;
  unsigned c3 = (base + 3 < M_KEYS) ? cnt[base + 3] : 0u;
  unsigned tot = c0 + c1 + c2 + c3;
  sb[t] = tot;
  __syncthreads();
  for (int off = 1; off < 256; off <<= 1) {
    unsigned v = (t >= off) ? sb[t - off] : 0u;
    __syncthreads();
    sb[t] += v;
    __syncthreads();
  }
  unsigned run = boff[blockIdx.x] + (sb[t] - tot);
  if (base + 0 < M_KEYS) rowstart[base + 0] = (int)run; run += c0;
  if (base + 1 < M_KEYS) rowstart[base + 1] = (int)run; run += c1;
  if (base + 2 < M_KEYS) rowstart[base + 2] = (int)run; run += c2;
  if (base + 3 < M_KEYS) rowstart[base + 3] = (int)run;
}

// pass 2: place ((src*HW+rel*64)<<3 | rel) via precomputed rank (no atomics)
__global__ void k_place(const int* __restrict__ src, const int* __restrict__ dst,
                        const int* __restrict__ ty, const int* __restrict__ rank,
                        const int* __restrict__ rowstart, unsigned* __restrict__ eb) {
  int e = blockIdx.x * 256 + threadIdx.x;
  if (e < NE) {
    int t = ty[e];
    int key = dst[e] * NR + t;
    unsigned off = (unsigned)(src[e] * HW + t * 64);
    eb[rowstart[key] + rank[e]] = (off << 3) | (unsigned)t;
  }
}

// wt[c][k] bf16, c<576 output cols of [W_0..W_7 | root], k<F
template <int F>
__global__ void k_wconv(const float* __restrict__ convw, const float* __restrict__ root,
                        ushort_t* __restrict__ wt) {
  int i = blockIdx.x * 256 + threadIdx.x;  // over 576*F
  if (i >= 576 * F) return;
  int c = i / F, k = i % F;
  float v = (c < 512) ? convw[((size_t)(c >> 6) * F + k) * 64 + (c & 63)]
                      : root[(size_t)k * 64 + (c & 63)];
  wt[(size_t)c * F + k] = f2bf(v);
}

// Persistent fused BN+ReLU+hi/lo-split + MFMA xform (round-12/13 proven).
template <int F, bool APPLY_BN>
__global__ __launch_bounds__(256) void k_xmm(
    const float* __restrict__ xin, const float* __restrict__ scsh,
    const ushort_t* __restrict__ wt, ushort_t* __restrict__ h) {
  constexpr int KK = 2 * F;
  constexpr int XPAD = KK + 8;
  constexpr int LDR = 592;
  __shared__ ushort_t xs[16 * XPAD];
  __shared__ ushort_t ot[16 * LDR];
  int lane = threadIdx.x & 63;
  int w = threadIdx.x >> 6;
  int m = lane & 15;
  int q = lane >> 4;
  int ct0 = w * 9;

  short8 bfrag[9 * (F / 32)];
  #pragma unroll
  for (int ks = 0; ks < F / 32; ks++)
    #pragma unroll
    for (int t = 0; t < 9; t++)
      bfrag[ks * 9 + t] =
          *(const short8*)(wt + (size_t)((ct0 + t) * 16 + m) * F + ks * 32 + q * 8);

  for (int tile = blockIdx.x; tile < NN / 16; tile += gridDim.x) {
    int nbase = tile * 16;
    for (int i = threadIdx.x; i < 16 * F; i += 256) {
      int r = i / F, k = i - r * F;
      float v = xin[(size_t)(nbase + r) * F + k];
      if (APPLY_BN) v = fmaxf(fmaf(v, scsh[k], scsh[64 + k]), 0.0f);
      ushort_t hi = f2bf(v);
      xs[r * XPAD + k] = hi;
      xs[r * XPAD + F + k] = f2bf(v - bf2f(hi));
    }
    __syncthreads();

    short8 afrag[2 * (F / 32)];
    #pragma unroll
    for (int ks = 0; ks < F / 32; ks++) {
      afrag[2 * ks + 0] = *(const short8*)&xs[m * XPAD + ks * 32 + q * 8];
      afrag[2 * ks + 1] = *(const short8*)&xs[m * XPAD + F + ks * 32 + q * 8];
    }

    f32x4 acc[9];
    #pragma unroll
    for (int t = 0; t < 9; t++) acc[t] = (f32x4){0.f, 0.f, 0.f, 0.f};
    #pragma unroll
    for (int ks = 0; ks < F / 32; ks++) {
      #pragma unroll
      for (int t = 0; t < 9; t++) {
        acc[t] = __builtin_amdgcn_mfma_f32_16x16x32_bf16(afrag[2 * ks + 0],
                                                         bfrag[ks * 9 + t], acc[t], 0, 0, 0);
        acc[t] = __builtin_amdgcn_mfma_f32_16x16x32_bf16(afrag[2 * ks + 1],
                                                         bfrag[ks * 9 + t], acc[t], 0, 0, 0);
      }
    }
    #pragma unroll
    for (int t = 0; t < 9; t++) {
      int col = (ct0 + t) * 16 + m;
      #pragma unroll
      for (int j = 0; j < 4; j++) {
        int row = q * 4 + j;
        ot[row * LDR + col] = f2bf(acc[t][j]);
      }
    }
    __syncthreads();
    u32x4* dst = (u32x4*)(h + (size_t)nbase * HW);
    for (int idx = threadIdx.x; idx < 16 * 72; idx += 256) {
      int row = idx / 72, i = idx - row * 72;
      dst[row * 72 + i] = *(const u32x4*)&ot[row * LDR + i * 8];
    }
  }
}

// Two-nodes-per-wave aggregation (round-16 win) on key-level CSR (round-15
// preprocess): each 32-lane half owns one node; 4 edge streams x 8 lanes x
// uint4 (8 bf16 channels); invcnt from rowstart diffs; perm+dot2 pairs;
// 2-level shfl_xor combine. Fixed costs amortize over 2 nodes.
__global__ __launch_bounds__(256) void k_agg4(
    const ushort_t* __restrict__ h, const int* __restrict__ rs,
    const unsigned* __restrict__ eb, const float* __restrict__ bias,
    float* __restrict__ outp, float* __restrict__ statsrep) {
  __shared__ float red[1024];      // [0..511] sums, [512..1023] squares
  __shared__ ushort_t iclu[8][8];
  int lane = threadIdx.x & 63, w = threadIdx.x >> 6;
  int hw = lane >> 5;              // half 0/1
  int nd = w * 2 + hw;             // node slot 0..7
  int n = blockIdx.x * 8 + nd;
  int l32 = lane & 31;
  if (l32 < 8) {
    int c = rs[n * NR + l32 + 1] - rs[n * NR + l32];
    iclu[nd][l32] = f2bf(1.0f / (float)(c > 1 ? c : 1));
  }
  int lo = rs[n * NR];
  int cnt = rs[n * NR + NR] - lo;
  __syncthreads();
  int g = (lane >> 3) & 3;         // stream in half
  int c8 = (lane & 7) * 8;         // channel base
  int cntmax = max(cnt, __shfl_xor(cnt, 32));
  float a[8];
  #pragma unroll
  for (int j = 0; j < 8; j++) a[j] = 0.f;
  for (int base = 0; base < cntmax; base += 16) {
    unsigned rec[4]; u32x4 hv[4]; unsigned icb[4];
    #pragma unroll
    for (int s = 0; s < 4; s++) {
      int el = base + s * 4 + g;
      int ee = (el < cnt) ? el : (cnt > 0 ? cnt - 1 : 0);
      rec[s] = eb[lo + ee];
      icb[s] = (el < cnt) ? (unsigned)iclu[nd][rec[s] & 7] : 0u;
    }
    #pragma unroll
    for (int s = 0; s < 4; s++)
      hv[s] = *(const u32x4*)(h + (size_t)(rec[s] >> 3) + c8);
#if USE_DOT2
    #pragma unroll
    for (int s = 0; s < 4; s += 2) {
      unsigned b01 = __builtin_amdgcn_perm(icb[s + 1], icb[s], 0x05040100u);
      bf16x2 bb = __builtin_bit_cast(bf16x2, b01);
      #pragma unroll
      for (int k = 0; k < 4; k++) {
        unsigned plo = __builtin_amdgcn_perm(hv[s + 1][k], hv[s][k], 0x05040100u);
        unsigned phi = __builtin_amdgcn_perm(hv[s + 1][k], hv[s][k], 0x07060302u);
        a[2 * k + 0] = __builtin_amdgcn_fdot2_f32_bf16(
            __builtin_bit_cast(bf16x2, plo), bb, a[2 * k + 0], false);
        a[2 * k + 1] = __builtin_amdgcn_fdot2_f32_bf16(
            __builtin_bit_cast(bf16x2, phi), bb, a[2 * k + 1], false);
      }
    }
#else
    #pragma unroll
    for (int s = 0; s < 4; s++) {
      float ic = bf2f((ushort_t)icb[s]);
      #pragma unroll
      for (int k = 0; k < 4; k++) {
        a[2 * k + 0] = fmaf(__uint_as_float(hv[s][k] << 16), ic, a[2 * k + 0]);
        a[2 * k + 1] = fmaf(__uint_as_float(hv[s][k] & 0xffff0000u), ic, a[2 * k + 1]);
      }
    }
#endif
  }
  #pragma unroll
  for (int j = 0; j < 8; j++) {
    a[j] += __shfl_xor(a[j], 8);
    a[j] += __shfl_xor(a[j], 16);
  }
  if (g == 0) {  // lanes l32<8 hold final 8-channel sums for node nd
    u32x4 sv = *(const u32x4*)(h + (size_t)n * HW + 512 + c8);
    float4 b4lo = *(const float4*)(bias + c8);
    float4 b4hi = *(const float4*)(bias + c8 + 4);
    float d[8];
    d[0] = a[0] + __uint_as_float(sv[0] << 16) + b4lo.x;
    d[1] = a[1] + __uint_as_float(sv[0] & 0xffff0000u) + b4lo.y;
    d[2] = a[2] + __uint_as_float(sv[1] << 16) + b4lo.z;
    d[3] = a[3] + __uint_as_float(sv[1] & 0xffff0000u) + b4lo.w;
    d[4] = a[4] + __uint_as_float(sv[2] << 16) + b4hi.x;
    d[5] = a[5] + __uint_as_float(sv[2] & 0xffff0000u) + b4hi.y;
    d[6] = a[6] + __uint_as_float(sv[3] << 16) + b4hi.z;
    d[7] = a[7] + __uint_as_float(sv[3] & 0xffff0000u) + b4hi.w;
    float4 lo4 = make_float4(d[0], d[1], d[2], d[3]);
    float4 hi4 = make_float4(d[4], d[5], d[6], d[7]);
    *(float4*)(outp + (size_t)n * HD + c8) = lo4;
    *(float4*)(outp + (size_t)n * HD + c8 + 4) = hi4;
    *(float4*)(&red[nd * 64 + c8]) = lo4;
    *(float4*)(&red[nd * 64 + c8 + 4]) = hi4;
    *(float4*)(&red[512 + nd * 64 + c8]) =
        make_float4(d[0] * d[0], d[1] * d[1], d[2] * d[2], d[3] * d[3]);
    *(float4*)(&red[512 + nd * 64 + c8 + 4]) =
        make_float4(d[4] * d[4], d[5] * d[5], d[6] * d[6], d[7] * d[7]);
  }
  __syncthreads();
  if (w == 0) {
    float ts = 0.f, tss = 0.f;
    #pragma unroll
    for (int k = 0; k < 8; k++) {
      ts += red[k * 64 + lane];
      tss += red[512 + k * 64 + lane];
    }
    int rp = blockIdx.x & (RREP - 1);
    atomicAdd(&statsrep[rp * 128 + lane], ts);
    atomicAdd(&statsrep[rp * 128 + 64 + lane], tss);
  }
}

// reduce stat replicas -> BN (scale, shift)
__global__ void k_finstats(const float* __restrict__ rep, const float* __restrict__ g,
                           const float* __restrict__ b, float* __restrict__ scsh) {
  int lane = threadIdx.x;  // 64
  float s = 0.f, ss = 0.f;
  for (int rp = 0; rp < RREP; rp++) {
    s += rep[rp * 128 + lane];
    ss += rep[rp * 128 + 64 + lane];
  }
  float mu = s * (1.0f / NN);
  float var = ss * (1.0f / NN) - mu * mu;
  float sc = g[lane] * rsqrtf(var + BN_EPS);
  scsh[lane] = sc;
  scsh[64 + lane] = b[lane] - mu * sc;
}

// sorted-batch segmented pooling over RAW layer outputs with inline BN+ReLU.
__global__ void k_poolseg(const float* __restrict__ t1, const float* __restrict__ t2,
                          const float* __restrict__ t3, const float* __restrict__ scsh,
                          const int* __restrict__ batch, float* __restrict__ psum,
                          unsigned* __restrict__ pmax, float* __restrict__ cntg) {
  __shared__ int bsh[PCH];
  int base = blockIdx.x * PCH;
  int c = threadIdx.x;  // 0..191
  for (int i = c; i < PCH; i += 192) bsh[i] = batch[base + i];
  __syncthreads();
  int L = c >> 6, cc = c & 63;
  const float* xs = (L == 0) ? t1 : (L == 1) ? t2 : t3;
  float sc = scsh[L * 128 + cc], sh = scsh[L * 128 + 64 + cc];
  int cur = bsh[0];
  float sum = 0.0f, mx = 0.0f;
  int runlen = 0;
  #pragma unroll 4
  for (int i = 0; i < PCH; i++) {
    int g = bsh[i];
    float v = fmaxf(fmaf(xs[(size_t)(base + i) * 64 + cc], sc, sh), 0.0f);
    if (g != cur) {  // wave-uniform, rare
      atomicAdd(&psum[cur * 192 + c], sum);
      atomicMax(&pmax[cur * 192 + c], __float_as_uint(mx));
      if (c == 0) atomicAdd(&cntg[cur], (float)runlen);
      cur = g; sum = 0.0f; mx = 0.0f; runlen = 0;
    }
    sum += v;
    mx = fmaxf(mx, v);
    runlen++;
  }
  atomicAdd(&psum[cur * 192 + c], sum);
  atomicMax(&pmax[cur * 192 + c], __float_as_uint(mx));
  if (c == 0) atomicAdd(&cntg[cur], (float)runlen);
}

__global__ void k_fc1(const float* __restrict__ psum, const unsigned* __restrict__ pmax,
                      const float* __restrict__ cntg, const float* __restrict__ w,
                      const float* __restrict__ bias, float* __restrict__ h1) {
  __shared__ float a[384];
  int g = blockIdx.x;
  float ic = 1.0f / fmaxf(cntg[g], 1.0f);
  for (int c = threadIdx.x; c < 384; c += 128) {
    a[c] = (c < 192) ? psum[g * 192 + c] * ic : __uint_as_float(pmax[g * 192 + (c - 192)]);
  }
  __syncthreads();
  int j = threadIdx.x;
  float acc = bias[j];
  for (int k = 0; k < 384; k++) acc = fmaf(a[k], w[k * 128 + j], acc);
  h1[g * 128 + j] = acc;
}

__global__ void k_fcbn_stats(const float* __restrict__ h1, const float* __restrict__ g,
                             const float* __restrict__ b, float* __restrict__ scsh) {
  __shared__ float sr[512], ssr[512];
  int j = threadIdx.x & 127, q = threadIdx.x >> 7;
  float s = 0.f, ss = 0.f;
  for (int i = q * 64; i < q * 64 + 64; i++) {
    float v = h1[i * 128 + j];
    s += v;
    ss = fmaf(v, v, ss);
  }
  sr[threadIdx.x] = s;
  ssr[threadIdx.x] = ss;
  __syncthreads();
  if (q == 0) {
    s = sr[j] + sr[128 + j] + sr[256 + j] + sr[384 + j];
    ss = ssr[j] + ssr[128 + j] + ssr[256 + j] + ssr[384 + j];
    float mu = s * (1.0f / NG);
    float var = ss * (1.0f / NG) - mu * mu;
    float sc = g[j] * rsqrtf(var + BN_EPS);
    scsh[j] = sc;
    scsh[128 + j] = b[j] - mu * sc;
  }
}

__global__ void k_leaky(float* __restrict__ h1, const float* __restrict__ scsh) {
  int j = threadIdx.x;
  int g = blockIdx.x;
  float v = fmaf(h1[g * 128 + j], scsh[j], scsh[128 + j]);
  h1[g * 128 + j] = v > 0.0f ? v : 0.2f * v;
}

__global__ void k_head(const float* __restrict__ h1, const float* __restrict__ fc2w,
                       const float* __restrict__ fc2b, const float* __restrict__ d1w,
                       const float* __restrict__ d1b, const float* __restrict__ d2w,
                       const float* __restrict__ d2b, float* __restrict__ out) {
  __shared__ float emb[16];
  int g = blockIdx.x;
  int t = threadIdx.x;  // 0..63
  if (t < 16) {
    float acc = fc2b[t];
    for (int k = 0; k < 128; k++) acc = fmaf(h1[g * 128 + k], fc2w[k * 16 + t], acc);
    emb[t] = acc;
    out[NG + g * 16 + t] = acc;
  }
  __syncthreads();
  float acc = d1b[t];
  for (int k = 0; k < 16; k++) acc = fmaf(emb[k], d1w[k * 64 + t], acc);
  acc = acc > 0.0f ? acc : 0.2f * acc;
  float p = acc * d2w[t];
  for (int off = 32; off > 0; off >>= 1) p += __shfl_down(p, off);
  if (t == 0) out[g] = p + d2b[0];
}

extern "C" void kernel_launch(void* const* d_in, const int* in_sizes, int n_in,
                              void* d_out, int out_size, void* d_ws, size_t ws_size,
                              hipStream_t stream) {
  const float* x    = (const float*)d_in[0];
  const int*   ei   = (const int*)d_in[1];
  const int*   ety  = (const int*)d_in[2];
  const int*   batch= (const int*)d_in[3];
  const float* c1w  = (const float*)d_in[4];
  const float* c1r  = (const float*)d_in[5];
  const float* c1b  = (const float*)d_in[6];
  const float* bn1g = (const float*)d_in[7];
  const float* bn1b = (const float*)d_in[8];
  const float* c2w  = (const float*)d_in[9];
  const float* c2r  = (const float*)d_in[10];
  const float* c2b  = (const float*)d_in[11];
  const float* bn2g = (const float*)d_in[12];
  const float* bn2b = (const float*)d_in[13];
  const float* c3w  = (const float*)d_in[14];
  const float* c3r  = (const float*)d_in[15];
  const float* c3b  = (const float*)d_in[16];
  const float* bn3g = (const float*)d_in[17];
  const float* bn3b = (const float*)d_in[18];
  const float* fc1w = (const float*)d_in[19];
  const float* fc1b = (const float*)d_in[20];
  const float* fbg  = (const float*)d_in[21];
  const float* fbb  = (const float*)d_in[22];
  const float* fc2w = (const float*)d_in[23];
  const float* fc2b = (const float*)d_in[24];
  const float* d1w  = (const float*)d_in[25];
  const float* d1b  = (const float*)d_in[26];
  const float* d2w  = (const float*)d_in[27];
  const float* d2b  = (const float*)d_in[28];
  const int* esrc = ei;
  const int* edst = ei + NE;
  float* out = (float*)d_out;

  float* W = (float*)d_ws;
  size_t o = 0;
  auto alloc = [&](size_t n) { float* p = W + o; o += (n + 63) & ~(size_t)63; return p; };
  unsigned* cnt      = (unsigned*)alloc(M_KEYS);
  float*    psum     = alloc(NG * 192);
  unsigned* pmax     = (unsigned*)alloc(NG * 192);
  float*    cntg     = alloc(NG);
  float*    statsrep = alloc(3 * RREP * 128);
  size_t zone = o;  // buffers [0, zone) zeroed every call
  int*      rowstart = (int*)alloc(M_KEYS + 1);
  int*      rank = (int*)alloc(NE);
  unsigned* eb   = (unsigned*)alloc(NE);
  unsigned* bsum = (unsigned*)alloc(1024);
  unsigned* boff = (unsigned*)alloc(1024);
  float*    scsh = alloc(3 * 128);
  float*    fcsc = alloc(256);
  float*    h1   = alloc(NG * 128);
  float*    tmp1 = alloc((size_t)NN * HD);
  float*    tmp2 = alloc((size_t)NN * HD);
  float*    tmp3 = alloc((size_t)NN * HD);
  ushort_t* hbig = (ushort_t*)alloc((size_t)NN * HW / 2);  // bf16 h
  ushort_t* wt1  = (ushort_t*)alloc(576 * FIN / 2);
  ushort_t* wt2  = (ushort_t*)alloc(576 * HD / 2);
  ushort_t* wt3  = (ushort_t*)alloc(576 * HD / 2);
  (void)ws_size; (void)in_sizes; (void)n_in; (void)out_size;

  // ---- preprocess: key-level CSR, rank-based placement (no hot atomics) ----
  k_zero<<<(int)((zone + 255) / 256), 256, 0, stream>>>(W, (int)zone);
  k_cnt<<<(NE + 255) / 256, 256, 0, stream>>>(edst, ety, cnt, rank);
  k_scanA<<<NB, 256, 0, stream>>>(cnt, bsum);
  k_scanB<<<1, 1024, 0, stream>>>(bsum, boff, rowstart);
  k_scanC<<<NB, 256, 0, stream>>>(cnt, boff, rowstart);
  k_place<<<(NE + 255) / 256, 256, 0, stream>>>(esrc, edst, ety, rank, rowstart, eb);
  k_wconv<FIN><<<(576 * FIN + 255) / 256, 256, 0, stream>>>(c1w, c1r, wt1);
  k_wconv<HD><<<(576 * HD + 255) / 256, 256, 0, stream>>>(c2w, c2r, wt2);
  k_wconv<HD><<<(576 * HD + 255) / 256, 256, 0, stream>>>(c3w, c3r, wt3);

  // ---- layers: persistent fused MFMA xform -> 2-node/wave aggregate ----
  k_xmm<FIN, false><<<2048, 256, 0, stream>>>(x, nullptr, wt1, hbig);
  k_agg4<<<NN / 8, 256, 0, stream>>>(hbig, rowstart, eb, c1b, tmp1, statsrep);
  k_finstats<<<1, 64, 0, stream>>>(statsrep, bn1g, bn1b, scsh);

  k_xmm<HD, true><<<2048, 256, 0, stream>>>(tmp1, scsh, wt2, hbig);
  k_agg4<<<NN / 8, 256, 0, stream>>>(hbig, rowstart, eb, c2b, tmp2, statsrep + RREP * 128);
  k_finstats<<<1, 64, 0, stream>>>(statsrep + RREP * 128, bn2g, bn2b, scsh + 128);

  k_xmm<HD, true><<<2048, 256, 0, stream>>>(tmp2, scsh + 128, wt3, hbig);
  k_agg4<<<NN / 8, 256, 0, stream>>>(hbig, rowstart, eb, c3b, tmp3, statsrep + 2 * RREP * 128);
  k_finstats<<<1, 64, 0, stream>>>(statsrep + 2 * RREP * 128, bn3g, bn3b, scsh + 256);

  // ---- pooling + head ----
  k_poolseg<<<NN / PCH, 192, 0, stream>>>(tmp1, tmp2, tmp3, scsh, batch, psum, pmax, cntg);
  k_fc1<<<NG, 128, 0, stream>>>(psum, pmax, cntg, fc1w, fc1b, h1);
  k_fcbn_stats<<<1, 512, 0, stream>>>(h1, fbg, fbb, fcsc);
  k_leaky<<<NG, 128, 0, stream>>>(h1, fcsc);
  k_head<<<NG, 64, 0, stream>>>(h1, fc2w, fc2b, d1w, d1b, d2w, d2b, out);
}

// Round 18
// 406.288 us; speedup vs baseline: 1.1323x; 1.0077x over previous
//
#include <hip/hip_runtime.h>

#define NN 100000
#define NE 1250000
#define FIN 32
#define HD 64
#define NR 8
#define NG 256
#define BN_EPS 1e-5f
#define PCH 100          // nodes per pooling block (divides NN)
#define M_KEYS (NN * NR) // 800000 (dst,rel) segments
#define NB 782           // scan blocks: 782*1024 >= 800000
#define RREP 32          // BN-stat atomic replicas
#define HW 576           // h width: 8 rel * 64 + root 64
#define XCGRID 1792      // k_xc grid: 7 blocks/CU x 256 CU, parity-split roles

#if defined(__has_builtin)
#if __has_builtin(__builtin_amdgcn_fdot2_f32_bf16)
#define USE_DOT2 1
#endif
#endif
#ifndef USE_DOT2
#define USE_DOT2 0
#endif

typedef unsigned short ushort_t;
typedef __attribute__((ext_vector_type(8))) short short8;
typedef __attribute__((ext_vector_type(4))) float f32x4;
typedef __attribute__((ext_vector_type(4))) unsigned int u32x4;
#if USE_DOT2
typedef __bf16 bf16x2 __attribute__((ext_vector_type(2)));
#endif

static __device__ __forceinline__ ushort_t f2bf(float f) {
  unsigned u = __float_as_uint(f);
  u += 0x7fffu + ((u >> 16) & 1u);  // RNE
  return (ushort_t)(u >> 16);
}
static __device__ __forceinline__ float bf2f(ushort_t b) {
  return __uint_as_float((unsigned)b << 16);
}

__global__ void k_zero(float* __restrict__ p, int n) {
  int i = blockIdx.x * 256 + threadIdx.x;
  if (i < n) p[i] = 0.0f;
}

// Fused front: parity-interleaved roles so both kinds co-reside on every CU.
// Even blocks: persistent MFMA xform for layer 1 (B frags in registers).
// Odd blocks: grid-stride per-(dst,rel) count + rank pass (independent work).
__global__ __launch_bounds__(256) void k_xc(
    const float* __restrict__ xin, const ushort_t* __restrict__ wt,
    ushort_t* __restrict__ h, const int* __restrict__ dst,
    const int* __restrict__ ty, unsigned* __restrict__ cnt,
    int* __restrict__ rank) {
  constexpr int F = FIN;
  constexpr int KK = 2 * F;
  constexpr int XPAD = KK + 8;
  constexpr int LDR = 592;
  __shared__ ushort_t xs[16 * XPAD];
  __shared__ ushort_t ot[16 * LDR];
  if (blockIdx.x & 1) {
    // ---- cnt role ----
    int stride = (XCGRID / 2) * 256;
    for (int e = (blockIdx.x >> 1) * 256 + threadIdx.x; e < NE; e += stride) {
      int key = dst[e] * NR + ty[e];
      rank[e] = (int)atomicAdd(&cnt[key], 1u);
    }
    return;
  }
  // ---- xmm role (layer 1, no BN) ----
  int lane = threadIdx.x & 63;
  int w = threadIdx.x >> 6;
  int m = lane & 15;
  int q = lane >> 4;
  int ct0 = w * 9;
  short8 bfrag[9 * (F / 32)];
  #pragma unroll
  for (int ks = 0; ks < F / 32; ks++)
    #pragma unroll
    for (int t = 0; t < 9; t++)
      bfrag[ks * 9 + t] =
          *(const short8*)(wt + (size_t)((ct0 + t) * 16 + m) * F + ks * 32 + q * 8);

  for (int tile = blockIdx.x >> 1; tile < NN / 16; tile += XCGRID / 2) {
    int nbase = tile * 16;
    for (int i = threadIdx.x; i < 16 * F; i += 256) {
      int r = i / F, k = i - r * F;
      float v = xin[(size_t)(nbase + r) * F + k];
      ushort_t hi = f2bf(v);
      xs[r * XPAD + k] = hi;
      xs[r * XPAD + F + k] = f2bf(v - bf2f(hi));
    }
    __syncthreads();
    short8 afrag[2 * (F / 32)];
    #pragma unroll
    for (int ks = 0; ks < F / 32; ks++) {
      afrag[2 * ks + 0] = *(const short8*)&xs[m * XPAD + ks * 32 + q * 8];
      afrag[2 * ks + 1] = *(const short8*)&xs[m * XPAD + F + ks * 32 + q * 8];
    }
    f32x4 acc[9];
    #pragma unroll
    for (int t = 0; t < 9; t++) acc[t] = (f32x4){0.f, 0.f, 0.f, 0.f};
    #pragma unroll
    for (int ks = 0; ks < F / 32; ks++) {
      #pragma unroll
      for (int t = 0; t < 9; t++) {
        acc[t] = __builtin_amdgcn_mfma_f32_16x16x32_bf16(afrag[2 * ks + 0],
                                                         bfrag[ks * 9 + t], acc[t], 0, 0, 0);
        acc[t] = __builtin_amdgcn_mfma_f32_16x16x32_bf16(afrag[2 * ks + 1],
                                                         bfrag[ks * 9 + t], acc[t], 0, 0, 0);
      }
    }
    #pragma unroll
    for (int t = 0; t < 9; t++) {
      int col = (ct0 + t) * 16 + m;
      #pragma unroll
      for (int j = 0; j < 4; j++) {
        int row = q * 4 + j;
        ot[row * LDR + col] = f2bf(acc[t][j]);
      }
    }
    __syncthreads();
    u32x4* dp = (u32x4*)(h + (size_t)nbase * HW);
    for (int idx = threadIdx.x; idx < 16 * 72; idx += 256) {
      int row = idx / 72, i = idx - row * 72;
      dp[row * 72 + i] = *(const u32x4*)&ot[row * LDR + i * 8];
    }
  }
}

// hierarchical exclusive scan of cnt[M_KEYS] -> rowstart[M_KEYS+1]
__global__ void k_scanA(const unsigned* __restrict__ cnt, unsigned* __restrict__ bsum) {
  __shared__ unsigned red[256];
  int t = threadIdx.x;
  int base = blockIdx.x * 1024 + t * 4;
  unsigned s = 0;
  #pragma unroll
  for (int i = 0; i < 4; i++) {
    int idx = base + i;
    if (idx < M_KEYS) s += cnt[idx];
  }
  red[t] = s;
  __syncthreads();
  for (int off = 128; off > 0; off >>= 1) {
    if (t < off) red[t] += red[t + off];
    __syncthreads();
  }
  if (t == 0) bsum[blockIdx.x] = red[0];
}

__global__ __launch_bounds__(1024) void k_scanB(const unsigned* __restrict__ bsum,
                                                unsigned* __restrict__ boff,
                                                int* __restrict__ rowstart) {
  __shared__ unsigned sb[1024];
  int t = threadIdx.x;
  unsigned mine = (t < NB) ? bsum[t] : 0u;
  sb[t] = mine;
  __syncthreads();
  for (int off = 1; off < 1024; off <<= 1) {
    unsigned v = (t >= off) ? sb[t - off] : 0u;
    __syncthreads();
    sb[t] += v;
    __syncthreads();
  }
  if (t < NB) boff[t] = sb[t] - mine;
  if (t == 1023) rowstart[M_KEYS] = (int)sb[1023];
}

__global__ void k_scanC(const unsigned* __restrict__ cnt, const unsigned* __restrict__ boff,
                        int* __restrict__ rowstart) {
  __shared__ unsigned sb[256];
  int t = threadIdx.x;
  int base = blockIdx.x * 1024 + t * 4;
  unsigned c0 = (base + 0 < M_KEYS) ? cnt[base + 0] : 0u;
  unsigned c1 = (base + 1 < M_KEYS) ? cnt[base + 1] : 0u;
  unsigned c2 = (base + 2 < M_KEYS) ? cnt[base + 2] : 0u;
  unsigned c3 = (base + 3 < M_KEYS) ? cnt[base + 3] : 0u;
  unsigned tot = c0 + c1 + c2 + c3;
  sb[t] = tot;
  __syncthreads();
  for (int off = 1; off < 256; off <<= 1) {
    unsigned v = (t >= off) ? sb[t - off] : 0u;
    __syncthreads();
    sb[t] += v;
    __syncthreads();
  }
  unsigned run = boff[blockIdx.x] + (sb[t] - tot);
  if (base + 0 < M_KEYS) rowstart[base + 0] = (int)run; run += c0;
  if (base + 1 < M_KEYS) rowstart[base + 1] = (int)run; run += c1;
  if (base + 2 < M_KEYS) rowstart[base + 2] = (int)run; run += c2;
  if (base + 3 < M_KEYS) rowstart[base + 3] = (int)run;
}

// place ((src*HW+rel*64)<<3 | rel) via precomputed rank (no atomics)
__global__ void k_place(const int* __restrict__ src, const int* __restrict__ dst,
                        const int* __restrict__ ty, const int* __restrict__ rank,
                        const int* __restrict__ rowstart, unsigned* __restrict__ eb) {
  int e = blockIdx.x * 256 + threadIdx.x;
  if (e < NE) {
    int t = ty[e];
    int key = dst[e] * NR + t;
    unsigned off = (unsigned)(src[e] * HW + t * 64);
    eb[rowstart[key] + rank[e]] = (off << 3) | (unsigned)t;
  }
}

// wt[c][k] bf16, c<576 output cols of [W_0..W_7 | root], k<F
template <int F>
__global__ void k_wconv(const float* __restrict__ convw, const float* __restrict__ root,
                        ushort_t* __restrict__ wt) {
  int i = blockIdx.x * 256 + threadIdx.x;  // over 576*F
  if (i >= 576 * F) return;
  int c = i / F, k = i % F;
  float v = (c < 512) ? convw[((size_t)(c >> 6) * F + k) * 64 + (c & 63)]
                      : root[(size_t)k * 64 + (c & 63)];
  wt[(size_t)c * F + k] = f2bf(v);
}

// Persistent fused BN+ReLU+hi/lo-split + MFMA xform (layers 2-3).
template <int F, bool APPLY_BN>
__global__ __launch_bounds__(256) void k_xmm(
    const float* __restrict__ xin, const float* __restrict__ scsh,
    const ushort_t* __restrict__ wt, ushort_t* __restrict__ h) {
  constexpr int KK = 2 * F;
  constexpr int XPAD = KK + 8;
  constexpr int LDR = 592;
  __shared__ ushort_t xs[16 * XPAD];
  __shared__ ushort_t ot[16 * LDR];
  int lane = threadIdx.x & 63;
  int w = threadIdx.x >> 6;
  int m = lane & 15;
  int q = lane >> 4;
  int ct0 = w * 9;

  short8 bfrag[9 * (F / 32)];
  #pragma unroll
  for (int ks = 0; ks < F / 32; ks++)
    #pragma unroll
    for (int t = 0; t < 9; t++)
      bfrag[ks * 9 + t] =
          *(const short8*)(wt + (size_t)((ct0 + t) * 16 + m) * F + ks * 32 + q * 8);

  for (int tile = blockIdx.x; tile < NN / 16; tile += gridDim.x) {
    int nbase = tile * 16;
    for (int i = threadIdx.x; i < 16 * F; i += 256) {
      int r = i / F, k = i - r * F;
      float v = xin[(size_t)(nbase + r) * F + k];
      if (APPLY_BN) v = fmaxf(fmaf(v, scsh[k], scsh[64 + k]), 0.0f);
      ushort_t hi = f2bf(v);
      xs[r * XPAD + k] = hi;
      xs[r * XPAD + F + k] = f2bf(v - bf2f(hi));
    }
    __syncthreads();

    short8 afrag[2 * (F / 32)];
    #pragma unroll
    for (int ks = 0; ks < F / 32; ks++) {
      afrag[2 * ks + 0] = *(const short8*)&xs[m * XPAD + ks * 32 + q * 8];
      afrag[2 * ks + 1] = *(const short8*)&xs[m * XPAD + F + ks * 32 + q * 8];
    }

    f32x4 acc[9];
    #pragma unroll
    for (int t = 0; t < 9; t++) acc[t] = (f32x4){0.f, 0.f, 0.f, 0.f};
    #pragma unroll
    for (int ks = 0; ks < F / 32; ks++) {
      #pragma unroll
      for (int t = 0; t < 9; t++) {
        acc[t] = __builtin_amdgcn_mfma_f32_16x16x32_bf16(afrag[2 * ks + 0],
                                                         bfrag[ks * 9 + t], acc[t], 0, 0, 0);
        acc[t] = __builtin_amdgcn_mfma_f32_16x16x32_bf16(afrag[2 * ks + 1],
                                                         bfrag[ks * 9 + t], acc[t], 0, 0, 0);
      }
    }
    #pragma unroll
    for (int t = 0; t < 9; t++) {
      int col = (ct0 + t) * 16 + m;
      #pragma unroll
      for (int j = 0; j < 4; j++) {
        int row = q * 4 + j;
        ot[row * LDR + col] = f2bf(acc[t][j]);
      }
    }
    __syncthreads();
    u32x4* dst = (u32x4*)(h + (size_t)nbase * HW);
    for (int idx = threadIdx.x; idx < 16 * 72; idx += 256) {
      int row = idx / 72, i = idx - row * 72;
      dst[row * 72 + i] = *(const u32x4*)&ot[row * LDR + i * 8];
    }
  }
}

// Two-nodes-per-wave aggregation on key-level CSR (round-17 proven).
__global__ __launch_bounds__(256) void k_agg4(
    const ushort_t* __restrict__ h, const int* __restrict__ rs,
    const unsigned* __restrict__ eb, const float* __restrict__ bias,
    float* __restrict__ outp, float* __restrict__ statsrep) {
  __shared__ float red[1024];      // [0..511] sums, [512..1023] squares
  __shared__ ushort_t iclu[8][8];
  int lane = threadIdx.x & 63, w = threadIdx.x >> 6;
  int hw = lane >> 5;              // half 0/1
  int nd = w * 2 + hw;             // node slot 0..7
  int n = blockIdx.x * 8 + nd;
  int l32 = lane & 31;
  if (l32 < 8) {
    int c = rs[n * NR + l32 + 1] - rs[n * NR + l32];
    iclu[nd][l32] = f2bf(1.0f / (float)(c > 1 ? c : 1));
  }
  int lo = rs[n * NR];
  int cnt = rs[n * NR + NR] - lo;
  __syncthreads();
  int g = (lane >> 3) & 3;         // stream in half
  int c8 = (lane & 7) * 8;         // channel base
  int cntmax = max(cnt, __shfl_xor(cnt, 32));
  float a[8];
  #pragma unroll
  for (int j = 0; j < 8; j++) a[j] = 0.f;
  for (int base = 0; base < cntmax; base += 16) {
    unsigned rec[4]; u32x4 hv[4]; unsigned icb[4];
    #pragma unroll
    for (int s = 0; s < 4; s++) {
      int el = base + s * 4 + g;
      int ee = (el < cnt) ? el : (cnt > 0 ? cnt - 1 : 0);
      rec[s] = eb[lo + ee];
      icb[s] = (el < cnt) ? (unsigned)iclu[nd][rec[s] & 7] : 0u;
    }
    #pragma unroll
    for (int s = 0; s < 4; s++)
      hv[s] = *(const u32x4*)(h + (size_t)(rec[s] >> 3) + c8);
#if USE_DOT2
    #pragma unroll
    for (int s = 0; s < 4; s += 2) {
      unsigned b01 = __builtin_amdgcn_perm(icb[s + 1], icb[s], 0x05040100u);
      bf16x2 bb = __builtin_bit_cast(bf16x2, b01);
      #pragma unroll
      for (int k = 0; k < 4; k++) {
        unsigned plo = __builtin_amdgcn_perm(hv[s + 1][k], hv[s][k], 0x05040100u);
        unsigned phi = __builtin_amdgcn_perm(hv[s + 1][k], hv[s][k], 0x07060302u);
        a[2 * k + 0] = __builtin_amdgcn_fdot2_f32_bf16(
            __builtin_bit_cast(bf16x2, plo), bb, a[2 * k + 0], false);
        a[2 * k + 1] = __builtin_amdgcn_fdot2_f32_bf16(
            __builtin_bit_cast(bf16x2, phi), bb, a[2 * k + 1], false);
      }
    }
#else
    #pragma unroll
    for (int s = 0; s < 4; s++) {
      float ic = bf2f((ushort_t)icb[s]);
      #pragma unroll
      for (int k = 0; k < 4; k++) {
        a[2 * k + 0] = fmaf(__uint_as_float(hv[s][k] << 16), ic, a[2 * k + 0]);
        a[2 * k + 1] = fmaf(__uint_as_float(hv[s][k] & 0xffff0000u), ic, a[2 * k + 1]);
      }
    }
#endif
  }
  #pragma unroll
  for (int j = 0; j < 8; j++) {
    a[j] += __shfl_xor(a[j], 8);
    a[j] += __shfl_xor(a[j], 16);
  }
  if (g == 0) {  // lanes l32<8 hold final 8-channel sums for node nd
    u32x4 sv = *(const u32x4*)(h + (size_t)n * HW + 512 + c8);
    float4 b4lo = *(const float4*)(bias + c8);
    float4 b4hi = *(const float4*)(bias + c8 + 4);
    float d[8];
    d[0] = a[0] + __uint_as_float(sv[0] << 16) + b4lo.x;
    d[1] = a[1] + __uint_as_float(sv[0] & 0xffff0000u) + b4lo.y;
    d[2] = a[2] + __uint_as_float(sv[1] << 16) + b4lo.z;
    d[3] = a[3] + __uint_as_float(sv[1] & 0xffff0000u) + b4lo.w;
    d[4] = a[4] + __uint_as_float(sv[2] << 16) + b4hi.x;
    d[5] = a[5] + __uint_as_float(sv[2] & 0xffff0000u) + b4hi.y;
    d[6] = a[6] + __uint_as_float(sv[3] << 16) + b4hi.z;
    d[7] = a[7] + __uint_as_float(sv[3] & 0xffff0000u) + b4hi.w;
    float4 lo4 = make_float4(d[0], d[1], d[2], d[3]);
    float4 hi4 = make_float4(d[4], d[5], d[6], d[7]);
    *(float4*)(outp + (size_t)n * HD + c8) = lo4;
    *(float4*)(outp + (size_t)n * HD + c8 + 4) = hi4;
    *(float4*)(&red[nd * 64 + c8]) = lo4;
    *(float4*)(&red[nd * 64 + c8 + 4]) = hi4;
    *(float4*)(&red[512 + nd * 64 + c8]) =
        make_float4(d[0] * d[0], d[1] * d[1], d[2] * d[2], d[3] * d[3]);
    *(float4*)(&red[512 + nd * 64 + c8 + 4]) =
        make_float4(d[4] * d[4], d[5] * d[5], d[6] * d[6], d[7] * d[7]);
  }
  __syncthreads();
  if (w == 0) {
    float ts = 0.f, tss = 0.f;
    #pragma unroll
    for (int k = 0; k < 8; k++) {
      ts += red[k * 64 + lane];
      tss += red[512 + k * 64 + lane];
    }
    int rp = blockIdx.x & (RREP - 1);
    atomicAdd(&statsrep[rp * 128 + lane], ts);
    atomicAdd(&statsrep[rp * 128 + 64 + lane], tss);
  }
}

// reduce stat replicas -> BN (scale, shift)
__global__ void k_finstats(const float* __restrict__ rep, const float* __restrict__ g,
                           const float* __restrict__ b, float* __restrict__ scsh) {
  int lane = threadIdx.x;  // 64
  float s = 0.f, ss = 0.f;
  for (int rp = 0; rp < RREP; rp++) {
    s += rep[rp * 128 + lane];
    ss += rep[rp * 128 + 64 + lane];
  }
  float mu = s * (1.0f / NN);
  float var = ss * (1.0f / NN) - mu * mu;
  float sc = g[lane] * rsqrtf(var + BN_EPS);
  scsh[lane] = sc;
  scsh[64 + lane] = b[lane] - mu * sc;
}

// sorted-batch segmented pooling over RAW layer outputs with inline BN+ReLU.
__global__ void k_poolseg(const float* __restrict__ t1, const float* __restrict__ t2,
                          const float* __restrict__ t3, const float* __restrict__ scsh,
                          const int* __restrict__ batch, float* __restrict__ psum,
                          unsigned* __restrict__ pmax, float* __restrict__ cntg) {
  __shared__ int bsh[PCH];
  int base = blockIdx.x * PCH;
  int c = threadIdx.x;  // 0..191
  for (int i = c; i < PCH; i += 192) bsh[i] = batch[base + i];
  __syncthreads();
  int L = c >> 6, cc = c & 63;
  const float* xs = (L == 0) ? t1 : (L == 1) ? t2 : t3;
  float sc = scsh[L * 128 + cc], sh = scsh[L * 128 + 64 + cc];
  int cur = bsh[0];
  float sum = 0.0f, mx = 0.0f;
  int runlen = 0;
  #pragma unroll 4
  for (int i = 0; i < PCH; i++) {
    int g = bsh[i];
    float v = fmaxf(fmaf(xs[(size_t)(base + i) * 64 + cc], sc, sh), 0.0f);
    if (g != cur) {  // wave-uniform, rare
      atomicAdd(&psum[cur * 192 + c], sum);
      atomicMax(&pmax[cur * 192 + c], __float_as_uint(mx));
      if (c == 0) atomicAdd(&cntg[cur], (float)runlen);
      cur = g; sum = 0.0f; mx = 0.0f; runlen = 0;
    }
    sum += v;
    mx = fmaxf(mx, v);
    runlen++;
  }
  atomicAdd(&psum[cur * 192 + c], sum);
  atomicMax(&pmax[cur * 192 + c], __float_as_uint(mx));
  if (c == 0) atomicAdd(&cntg[cur], (float)runlen);
}

__global__ void k_fc1(const float* __restrict__ psum, const unsigned* __restrict__ pmax,
                      const float* __restrict__ cntg, const float* __restrict__ w,
                      const float* __restrict__ bias, float* __restrict__ h1) {
  __shared__ float a[384];
  int g = blockIdx.x;
  float ic = 1.0f / fmaxf(cntg[g], 1.0f);
  for (int c = threadIdx.x; c < 384; c += 128) {
    a[c] = (c < 192) ? psum[g * 192 + c] * ic : __uint_as_float(pmax[g * 192 + (c - 192)]);
  }
  __syncthreads();
  int j = threadIdx.x;
  float acc = bias[j];
  for (int k = 0; k < 384; k++) acc = fmaf(a[k], w[k * 128 + j], acc);
  h1[g * 128 + j] = acc;
}

__global__ void k_fcbn_stats(const float* __restrict__ h1, const float* __restrict__ g,
                             const float* __restrict__ b, float* __restrict__ scsh) {
  __shared__ float sr[512], ssr[512];
  int j = threadIdx.x & 127, q = threadIdx.x >> 7;
  float s = 0.f, ss = 0.f;
  for (int i = q * 64; i < q * 64 + 64; i++) {
    float v = h1[i * 128 + j];
    s += v;
    ss = fmaf(v, v, ss);
  }
  sr[threadIdx.x] = s;
  ssr[threadIdx.x] = ss;
  __syncthreads();
  if (q == 0) {
    s = sr[j] + sr[128 + j] + sr[256 + j] + sr[384 + j];
    ss = ssr[j] + ssr[128 + j] + ssr[256 + j] + ssr[384 + j];
    float mu = s * (1.0f / NG);
    float var = ss * (1.0f / NG) - mu * mu;
    float sc = g[j] * rsqrtf(var + BN_EPS);
    scsh[j] = sc;
    scsh[128 + j] = b[j] - mu * sc;
  }
}

__global__ void k_leaky(float* __restrict__ h1, const float* __restrict__ scsh) {
  int j = threadIdx.x;
  int g = blockIdx.x;
  float v = fmaf(h1[g * 128 + j], scsh[j], scsh[128 + j]);
  h1[g * 128 + j] = v > 0.0f ? v : 0.2f * v;
}

__global__ void k_head(const float* __restrict__ h1, const float* __restrict__ fc2w,
                       const float* __restrict__ fc2b, const float* __restrict__ d1w,
                       const float* __restrict__ d1b, const float* __restrict__ d2w,
                       const float* __restrict__ d2b, float* __restrict__ out) {
  __shared__ float emb[16];
  int g = blockIdx.x;
  int t = threadIdx.x;  // 0..63
  if (t < 16) {
    float acc = fc2b[t];
    for (int k = 0; k < 128; k++) acc = fmaf(h1[g * 128 + k], fc2w[k * 16 + t], acc);
    emb[t] = acc;
    out[NG + g * 16 + t] = acc;
  }
  __syncthreads();
  float acc = d1b[t];
  for (int k = 0; k < 16; k++) acc = fmaf(emb[k], d1w[k * 64 + t], acc);
  acc = acc > 0.0f ? acc : 0.2f * acc;
  float p = acc * d2w[t];
  for (int off = 32; off > 0; off >>= 1) p += __shfl_down(p, off);
  if (t == 0) out[g] = p + d2b[0];
}

extern "C" void kernel_launch(void* const* d_in, const int* in_sizes, int n_in,
                              void* d_out, int out_size, void* d_ws, size_t ws_size,
                              hipStream_t stream) {
  const float* x    = (const float*)d_in[0];
  const int*   ei   = (const int*)d_in[1];
  const int*   ety  = (const int*)d_in[2];
  const int*   batch= (const int*)d_in[3];
  const float* c1w  = (const float*)d_in[4];
  const float* c1r  = (const float*)d_in[5];
  const float* c1b  = (const float*)d_in[6];
  const float* bn1g = (const float*)d_in[7];
  const float* bn1b = (const float*)d_in[8];
  const float* c2w  = (const float*)d_in[9];
  const float* c2r  = (const float*)d_in[10];
  const float* c2b  = (const float*)d_in[11];
  const float* bn2g = (const float*)d_in[12];
  const float* bn2b = (const float*)d_in[13];
  const float* c3w  = (const float*)d_in[14];
  const float* c3r  = (const float*)d_in[15];
  const float* c3b  = (const float*)d_in[16];
  const float* bn3g = (const float*)d_in[17];
  const float* bn3b = (const float*)d_in[18];
  const float* fc1w = (const float*)d_in[19];
  const float* fc1b = (const float*)d_in[20];
  const float* fbg  = (const float*)d_in[21];
  const float* fbb  = (const float*)d_in[22];
  const float* fc2w = (const float*)d_in[23];
  const float* fc2b = (const float*)d_in[24];
  const float* d1w  = (const float*)d_in[25];
  const float* d1b  = (const float*)d_in[26];
  const float* d2w  = (const float*)d_in[27];
  const float* d2b  = (const float*)d_in[28];
  const int* esrc = ei;
  const int* edst = ei + NE;
  float* out = (float*)d_out;

  float* W = (float*)d_ws;
  size_t o = 0;
  auto alloc = [&](size_t n) { float* p = W + o; o += (n + 63) & ~(size_t)63; return p; };
  unsigned* cnt      = (unsigned*)alloc(M_KEYS);
  float*    psum     = alloc(NG * 192);
  unsigned* pmax     = (unsigned*)alloc(NG * 192);
  float*    cntg     = alloc(NG);
  float*    statsrep = alloc(3 * RREP * 128);
  size_t zone = o;  // buffers [0, zone) zeroed every call
  int*      rowstart = (int*)alloc(M_KEYS + 1);
  int*      rank = (int*)alloc(NE);
  unsigned* eb   = (unsigned*)alloc(NE);
  unsigned* bsum = (unsigned*)alloc(1024);
  unsigned* boff = (unsigned*)alloc(1024);
  float*    scsh = alloc(3 * 128);
  float*    fcsc = alloc(256);
  float*    h1   = alloc(NG * 128);
  float*    tmp1 = alloc((size_t)NN * HD);
  float*    tmp2 = alloc((size_t)NN * HD);
  float*    tmp3 = alloc((size_t)NN * HD);
  ushort_t* hbig = (ushort_t*)alloc((size_t)NN * HW / 2);  // bf16 h
  ushort_t* wt1  = (ushort_t*)alloc(576 * FIN / 2);
  ushort_t* wt2  = (ushort_t*)alloc(576 * HD / 2);
  ushort_t* wt3  = (ushort_t*)alloc(576 * HD / 2);
  (void)ws_size; (void)in_sizes; (void)n_in; (void)out_size;

  // ---- front: zero + weights, then overlapped [xmm layer1 || cnt+rank] ----
  k_zero<<<(int)((zone + 255) / 256), 256, 0, stream>>>(W, (int)zone);
  k_wconv<FIN><<<(576 * FIN + 255) / 256, 256, 0, stream>>>(c1w, c1r, wt1);
  k_wconv<HD><<<(576 * HD + 255) / 256, 256, 0, stream>>>(c2w, c2r, wt2);
  k_wconv<HD><<<(576 * HD + 255) / 256, 256, 0, stream>>>(c3w, c3r, wt3);
  k_xc<<<XCGRID, 256, 0, stream>>>(x, wt1, hbig, edst, ety, cnt, rank);
  k_scanA<<<NB, 256, 0, stream>>>(cnt, bsum);
  k_scanB<<<1, 1024, 0, stream>>>(bsum, boff, rowstart);
  k_scanC<<<NB, 256, 0, stream>>>(cnt, boff, rowstart);
  k_place<<<(NE + 255) / 256, 256, 0, stream>>>(esrc, edst, ety, rank, rowstart, eb);

  // ---- layers ----
  k_agg4<<<NN / 8, 256, 0, stream>>>(hbig, rowstart, eb, c1b, tmp1, statsrep);
  k_finstats<<<1, 64, 0, stream>>>(statsrep, bn1g, bn1b, scsh);

  k_xmm<HD, true><<<2048, 256, 0, stream>>>(tmp1, scsh, wt2, hbig);
  k_agg4<<<NN / 8, 256, 0, stream>>>(hbig, rowstart, eb, c2b, tmp2, statsrep + RREP * 128);
  k_finstats<<<1, 64, 0, stream>>>(statsrep + RREP * 128, bn2g, bn2b, scsh + 128);

  k_xmm<HD, true><<<2048, 256, 0, stream>>>(tmp2, scsh + 128, wt3, hbig);
  k_agg4<<<NN / 8, 256, 0, stream>>>(hbig, rowstart, eb, c3b, tmp3, statsrep + 2 * RREP * 128);
  k_finstats<<<1, 64, 0, stream>>>(statsrep + 2 * RREP * 128, bn3g, bn3b, scsh + 256);

  // ---- pooling + head ----
  k_poolseg<<<NN / PCH, 192, 0, stream>>>(tmp1, tmp2, tmp3, scsh, batch, psum, pmax, cntg);
  k_fc1<<<NG, 128, 0, stream>>>(psum, pmax, cntg, fc1w, fc1b, h1);
  k_fcbn_stats<<<1, 512, 0, stream>>>(h1, fbg, fbb, fcsc);
  k_leaky<<<NG, 128, 0, stream>>>(h1, fcsc);
  k_head<<<NG, 64, 0, stream>>>(h1, fc2w, fc2b, d1w, d1b, d2w, d2b, out);
}